// Round 7
// baseline (224.033 us; speedup 1.0000x reference)
//
#include <hip/hip_runtime.h>
#include <math.h>

#define B_  2
#define S_  2048
#define D_  1024
#define H_  16
#define DK_ 64

typedef unsigned short u16;
typedef unsigned int u32;
typedef __bf16 bf16x8 __attribute__((ext_vector_type(8)));
typedef float f32x4 __attribute__((ext_vector_type(4)));
typedef float f32x16 __attribute__((ext_vector_type(16)));
typedef u32 u32x2 __attribute__((ext_vector_type(2)));
typedef u32 u32x4 __attribute__((ext_vector_type(4)));

typedef const __attribute__((address_space(1))) void* gas1_t;
typedef __attribute__((address_space(3))) void* las3_t;

__device__ __forceinline__ void gload_lds16(const void* g, void* l) {
    // async global->LDS, 16B per lane; LDS dst = wave-uniform base + lane*16
    __builtin_amdgcn_global_load_lds((gas1_t)g, (las3_t)l, 16, 0, 0);
}

__device__ __forceinline__ u16 f2bf(float f) {
    union { float f; unsigned u; } v; v.f = f;
    return (u16)((v.u + 0x7fffu + ((v.u >> 16) & 1u)) >> 16);   // RNE
}

// pack two f32 into two bf16 (RNE-ish round-half-up) in one u32: [lo | hi<<16]
__device__ __forceinline__ u32 pack_bf16_2(float lo, float hi) {
    union { float f; u32 u; } a, b;
    a.f = lo; b.f = hi;
    return __builtin_amdgcn_perm(b.u + 0x8000u, a.u + 0x8000u, 0x07060302u);
}

// single-instruction packed f32->bf16 (RNE), lo = src0, hi = src1
__device__ __forceinline__ u32 cvtpk_bf16(float lo, float hi) {
    u32 r;
    asm("v_cvt_pk_bf16_f32 %0, %1, %2" : "=v"(r) : "v"(lo), "v"(hi));
    return r;
}

// ---------------------------------------------------------------------------
// Fused fp32 -> bf16 cast over all 7 tensors + mask -> f32 factor (1 / 0)
// + per-batch masked-key count (softmax denominator correction).
// grid-stride (G11): 2048 tensor blocks x 8 float4/thread + 16 + 2.
// ---------------------------------------------------------------------------
__global__ __launch_bounds__(256)
void cast_all(const float* __restrict__ q, const float* __restrict__ k,
              const float* __restrict__ v, const float* __restrict__ wq,
              const float* __restrict__ wk, const float* __restrict__ wv,
              const float* __restrict__ wo, const int* __restrict__ mask,
              u16* __restrict__ qb, u16* __restrict__ kb, u16* __restrict__ vb,
              u16* __restrict__ wqb, u16* __restrict__ wkb, u16* __restrict__ wvb,
              u16* __restrict__ wob, float* __restrict__ mfac,
              float* __restrict__ nmaskf)
{
    const int bi = blockIdx.x;
    const int tid = threadIdx.x;
    if (bi >= 2064) {                  // masked-key count for batch b
        const int b = bi - 2064;
        __shared__ int red[256];
        int c = 0;
#pragma unroll
        for (int j = 0; j < 8; ++j)
            c += (mask[b * S_ + tid * 8 + j] == 0) ? 1 : 0;
        red[tid] = c;
        __syncthreads();
        for (int s = 128; s > 0; s >>= 1) {
            if (tid < s) red[tid] += red[tid + s];
            __syncthreads();
        }
        if (tid == 0) nmaskf[b] = (float)red[0];
        return;
    }
    if (bi >= 2048) {                  // mask -> float factor
        const int idx = (bi - 2048) * 256 + tid;
        mfac[idx] = mask[idx] ? 1.0f : 0.0f;
        return;
    }
#pragma unroll
    for (int j = 0; j < 8; ++j) {
        const int i = bi * 256 + tid + j * 524288;     // float4 index
        const float* src; u16* dst; int off;
        if (i < 3 * 1048576) {
            const int seg = i >> 20; off = i & 1048575;
            src = (seg == 0) ? q : (seg == 1) ? k : v;
            dst = (seg == 0) ? qb : (seg == 1) ? kb : vb;
        } else {
            const int jj = i - 3 * 1048576;
            const int seg = jj >> 18; off = jj & 262143;
            src = (seg == 0) ? wq : (seg == 1) ? wk : (seg == 2) ? wv : wo;
            dst = (seg == 0) ? wqb : (seg == 1) ? wkb : (seg == 2) ? wvb : wob;
        }
        const float4 val = ((const float4*)src)[off];
        uint2 o;
        o.x = pack_bf16_2(val.x, val.y);
        o.y = pack_bf16_2(val.z, val.w);
        ((uint2*)dst)[off] = o;
    }
}

// ---------------------------------------------------------------------------
// bf16 NT GEMM, BK=64, XOR-swizzled LDS (16B chunks, chunk ^= row&7) so
// fragment ds_read_b128 are conflict-free. 4 waves in 2x2. 16 K-iters.
// R7: double-buffered LDS, ONE barrier per K-iter: issue tile k+1's
// global_load_lds right after the barrier, compute tile k — hides the
// staging latency that the old load->barrier->compute pattern exposed
// in full every iteration (m233 2-phase stall).
// mode 0: fp32 out[m*D+n], bias[n]
// mode 1: bf16 out[((b*H+h)*S+s)*DK+dk] (split heads), bias[n], *scale,
//         optionally * rowfac[m]   (K projection: zero masked key rows)
// mode 3: bf16 out[m*4096+n], bias[m], optionally * colfac[n]  (V^T)
// ---------------------------------------------------------------------------
template<int BN>
__device__ __forceinline__ void gemm_body(
    const u16* __restrict__ A, const u16* __restrict__ W,
    const float* __restrict__ bias, void* __restrict__ outp,
    float scale, int mode, int m0, int n0,
    const float* __restrict__ rowfac, const float* __restrict__ colfac)
{
    constexpr int NJ = BN / 32;
    __shared__ u16 sA[2][128 * 64];   // 32 KB double-buffered
    __shared__ u16 sW[2][BN * 64];    // 32 or 16 KB double-buffered

    const int tid  = threadIdx.x;
    const int wave = tid >> 6, lane = tid & 63;
    const int quad = lane >> 4, l16 = lane & 15;
    const int wm = (wave >> 1) * 64;
    const int wn = (wave & 1) * (BN / 2);
    const int srow = lane >> 3;                 // row within 8-row staging group
    const int scol = ((lane & 7) ^ srow) * 8;   // swizzled source column (u16)
    const int sw7  = l16 & 7;

    f32x4 acc[4][NJ];
    const f32x4 zero = {0.f, 0.f, 0.f, 0.f};
#pragma unroll
    for (int i = 0; i < 4; ++i)
#pragma unroll
        for (int j = 0; j < NJ; ++j) acc[i][j] = zero;

    const u16* ast = A + (size_t)(m0 + wave * 8 + srow) * D_ + scol;
    const u16* wst = W + (size_t)(n0 + wave * 8 + srow) * D_ + scol;

    // prologue: stage K-tile 0 into buffer 0
#pragma unroll
    for (int t = 0; t < 4; ++t)
        gload_lds16(ast + (size_t)t * 32 * D_, sA[0] + (wave + t * 4) * 512);
#pragma unroll
    for (int t = 0; t < BN / 32; ++t)
        gload_lds16(wst + (size_t)t * 32 * D_, sW[0] + (wave + t * 4) * 512);

    for (int it = 0; it < 16; ++it) {
        __syncthreads();              // buf[cur] staged; prev iter's reads done
        const int cur = it & 1;

        if (it < 15) {                // issue next tile NOW (drains at next barrier)
            const int k0 = (it + 1) * 64;
#pragma unroll
            for (int t = 0; t < 4; ++t)
                gload_lds16(ast + (size_t)t * 32 * D_ + k0, sA[cur ^ 1] + (wave + t * 4) * 512);
#pragma unroll
            for (int t = 0; t < BN / 32; ++t)
                gload_lds16(wst + (size_t)t * 32 * D_ + k0, sW[cur ^ 1] + (wave + t * 4) * 512);
        }

#pragma unroll
        for (int kh = 0; kh < 2; ++kh) {
            const int phys = ((kh * 4 + quad) ^ sw7) * 8;
            bf16x8 af[4], bfr[NJ];
#pragma unroll
            for (int i = 0; i < 4; ++i)
                af[i] = *(const bf16x8*)(sA[cur] + (wm + i * 16 + l16) * 64 + phys);
#pragma unroll
            for (int j = 0; j < NJ; ++j)
                bfr[j] = *(const bf16x8*)(sW[cur] + (wn + j * 16 + l16) * 64 + phys);
#pragma unroll
            for (int i = 0; i < 4; ++i)
#pragma unroll
                for (int j = 0; j < NJ; ++j)
                    acc[i][j] = __builtin_amdgcn_mfma_f32_16x16x32_bf16(af[i], bfr[j], acc[i][j], 0, 0, 0);
        }
    }

    // Epilogue. C frag: row = quad*4+reg, col = lane&15
#pragma unroll
    for (int i = 0; i < 4; ++i) {
        float rf4[4];
        if (mode == 1 && rowfac) {
#pragma unroll
            for (int r = 0; r < 4; ++r)
                rf4[r] = rowfac[m0 + wm + i * 16 + quad * 4 + r];
        }
#pragma unroll
        for (int j = 0; j < NJ; ++j) {
            const int n = n0 + wn + j * 16 + l16;
            if (mode == 3) {
                const float cf = colfac ? colfac[n] : 1.0f;
#pragma unroll
                for (int r = 0; r < 4; ++r) {
                    const int mp = m0 + wm + i * 16 + quad * 4 + r;
                    ((u16*)outp)[(size_t)mp * (B_ * S_) + n] = f2bf((acc[i][j][r] + bias[mp]) * cf);
                }
            } else {
                const float bn = bias[n];
#pragma unroll
                for (int r = 0; r < 4; ++r) {
                    const int m = m0 + wm + i * 16 + quad * 4 + r;
                    float v = acc[i][j][r] + bn;
                    if (mode == 0) {
                        ((float*)outp)[(size_t)m * D_ + n] = v;
                    } else {
                        v *= scale;
                        if (rowfac) v *= rf4[r];
                        const int b = m >> 11, s = m & (S_ - 1);
                        const int h = n >> 6, dk = n & 63;
                        ((u16*)outp)[(((size_t)(b * H_ + h)) * S_ + s) * DK_ + dk] = f2bf(v);
                    }
                }
            }
        }
    }
}

// R7: 1D grid 768, bijective chunked XCD swizzle (T1): XCD k gets a
// contiguous 96-block chunk -> the 8 blocks sharing an A-panel land on ONE
// XCD (A fetched once) and the chunk's 8 W tiles (2MB) stay L2-resident.
__global__ __launch_bounds__(256)
void qkv_gemm(const u16* __restrict__ qin, const u16* __restrict__ kin, const u16* __restrict__ vin,
              const u16* __restrict__ wqb, const u16* __restrict__ wkb, const u16* __restrict__ wvb,
              const float* __restrict__ bq, const float* __restrict__ bk, const float* __restrict__ bv,
              u16* __restrict__ Qp, u16* __restrict__ Kp, u16* __restrict__ Vt,
              const float* __restrict__ mfac)
{
    const int bid = blockIdx.x;                      // 768 blocks
    const int swz = (bid & 7) * 96 + (bid >> 3);     // 768 = 8 * 96, bijective
    const int z   = swz >> 8;                        // 3 slices of 256
    const int rem = swz & 255;
    const int by  = rem >> 3;                        // 0..31 (128-row A tile)
    const int bx  = rem & 7;                         // 0..7  (128-row W tile)

    if (z == 2) {
        // V^T = Wv . value^T ; zero masked key columns via colfac
        gemm_body<128>(wvb, vin, bv, Vt, 1.0f, 3, bx * 128, by * 128,
                       nullptr, mfac);
    } else {
        const u16* A = (z == 0) ? qin : kin;
        const u16* W = (z == 0) ? wqb : wkb;
        const float* bias = (z == 0) ? bq : bk;
        u16* outp = (z == 0) ? Qp : Kp;
        // Q pre-scaled by log2(e)/sqrt(DK); K rows zeroed where masked
        const float scale = (z == 0) ? 0.18033688011112042f : 1.0f;
        const float* rf = (z == 1) ? mfac : nullptr;
        gemm_body<128>(A, W, bias, outp, scale, 1, by * 128, bx * 128,
                       rf, nullptr);
    }
}

__global__ __launch_bounds__(256)
void out_gemm(const u16* __restrict__ Xc, const u16* __restrict__ wob,
              const float* __restrict__ bo, float* __restrict__ out)
{
    const int bid = blockIdx.x;                      // 512 blocks
    const int swz = (bid & 7) * 64 + (bid >> 3);     // 512 = 8 * 64, bijective
    const int by  = swz >> 4;                        // 0..31
    const int bx  = swz & 15;                        // 0..15
    gemm_body<64>(Xc, wob, bo, out, 1.0f, 0, by * 128, bx * 64,
                  nullptr, nullptr);
}

// ---------------------------------------------------------------------------
// MFMA flash attention, S^T orientation, fixed-shift exp2 softmax, maskless.
//
// R5 structure (two independent 32-key streams/iter, Q in registers,
// permlane32_swap P exchange, cvt_pk pack) + R7 chunked XCD swizzle:
// the 16 q-tile blocks sharing a head's K/V go to one XCD (4 heads' K/V =
// 2MB, L2-resident).
// ---------------------------------------------------------------------------
__global__ __launch_bounds__(512, 4)
void attn_mfma(const u16* __restrict__ Qp, const u16* __restrict__ Kp,
               const u16* __restrict__ Vt, const float* __restrict__ nmaskf,
               u16* __restrict__ Xc)
{
    __shared__ u16 sKV[2][2][8192];  // [kg][buf][K0|K1|V0|V1] 64KB;
                                     // epilogue overlay: sO 32KB + sL 1KB

    const int tid  = threadIdx.x;
    const int wave = tid >> 6, lane = tid & 63;
    const int qg = wave & 3, kg = wave >> 2;
    const int l31 = lane & 31, hi = lane >> 5;
    const int bid = blockIdx.x;                      // 512 blocks
    const int swz = (bid & 7) * 64 + (bid >> 3);     // bijective chunk swizzle
    const int qt = swz & 15;
    const int bh = swz >> 4;
    const int b  = bh >> 4;
    const int h  = bh & 15;
    const int lr  = lane >> 3;          // staging row within 8-row group
    const int cl  = (lane & 7) ^ lr;    // logical chunk for pre-swizzled source
    const int sw5 = l31 & 7;            // row&7 for fragment reads

    const u16* Qb = Qp + ((size_t)bh * S_ + qt * 128) * DK_;
    const u16* Kb = Kp + (size_t)bh * S_ * DK_;
    // V staging: interleaved layout, physical row pr = qg*8+lr holds
    // dk = pr + 32*(cl>>2), key-chunk (cl&3)*8 of a 32-key sub-tile.
    const int vdk = (qg * 8 + lr) + 32 * (cl >> 2);
    const u16* Vsrc = Vt + (size_t)(h * 64 + vdk) * (B_ * S_) + b * S_ + (cl & 3) * 8;
    const u16* Ksrc = Kb + (size_t)(qg * 8 + lr) * DK_ + cl * 8;

    // Q straight to registers (no LDS): qf[ks] = Q[qg*32+l31][ks*16+hi*8+..8]
    bf16x8 qf[4];
    {
        const u16* qrow = Qb + (size_t)(qg * 32 + l31) * DK_ + hi * 8;
        qf[0] = *(const bf16x8*)(qrow);
        qf[1] = *(const bf16x8*)(qrow + 16);
        qf[2] = *(const bf16x8*)(qrow + 32);
        qf[3] = *(const bf16x8*)(qrow + 48);
    }

    // stage first 64-key chunk (c0 = kg): K sub0/sub1 + V sub0/sub1
    const u16* kpre = Ksrc + (size_t)kg * 64 * DK_;
    const u16* vpre = Vsrc + kg * 64;
    {
        u16* dst = sKV[kg][0];
        gload_lds16(kpre,                    dst + qg * 512);
        gload_lds16(kpre + (size_t)32 * DK_, dst + 2048 + qg * 512);
        gload_lds16(vpre,                    dst + 4096 + qg * 512);
        gload_lds16(vpre + 32,               dst + 6144 + qg * 512);
        kpre += (size_t)128 * DK_;
        vpre += 128;
    }

    f32x16 oc[2];                   // [dhalf]: col dk = dh*32+l31, rows q(reg,hi)
    const f32x16 z16 = {0.f,0.f,0.f,0.f,0.f,0.f,0.f,0.f,
                        0.f,0.f,0.f,0.f,0.f,0.f,0.f,0.f};
    oc[0] = z16; oc[1] = z16;
    float lsum = 0.f;               // partial row sum (own 16 keys per stream)

    for (int i = 0; i < 16; ++i) {      // group kg: 64-key chunk c = 2*i+kg
        __syncthreads();                // cur buf staged; prev iter's reads done
        const int cur = i & 1;

        // issue next chunk's staging NOW (async, drains at next top barrier)
        if (i < 15) {
            u16* dst = sKV[kg][cur ^ 1];
            gload_lds16(kpre,                    dst + qg * 512);
            gload_lds16(kpre + (size_t)32 * DK_, dst + 2048 + qg * 512);
            gload_lds16(vpre,                    dst + 4096 + qg * 512);
            gload_lds16(vpre + 32,               dst + 6144 + qg * 512);
            kpre += (size_t)128 * DK_;
            vpre += 128;
        }
        const u16* sKA = sKV[kg][cur];
        const u16* sKB = sKA + 2048;
        const u16* sVA = sKA + 4096;
        const u16* sVB = sKA + 6144;

        // ---- S^T for BOTH streams (independent 4-MFMA chains) ----
        f32x16 sfrA, sfrB;
        {
            const bf16x8 a0 = *(const bf16x8*)(sKA + l31 * 64 + (((0 + hi) ^ sw5)) * 8);
            const bf16x8 a1 = *(const bf16x8*)(sKA + l31 * 64 + (((2 + hi) ^ sw5)) * 8);
            const bf16x8 a2 = *(const bf16x8*)(sKA + l31 * 64 + (((4 + hi) ^ sw5)) * 8);
            const bf16x8 a3 = *(const bf16x8*)(sKA + l31 * 64 + (((6 + hi) ^ sw5)) * 8);
            const bf16x8 b0 = *(const bf16x8*)(sKB + l31 * 64 + (((0 + hi) ^ sw5)) * 8);
            const bf16x8 b1 = *(const bf16x8*)(sKB + l31 * 64 + (((2 + hi) ^ sw5)) * 8);
            const bf16x8 b2 = *(const bf16x8*)(sKB + l31 * 64 + (((4 + hi) ^ sw5)) * 8);
            const bf16x8 b3 = *(const bf16x8*)(sKB + l31 * 64 + (((6 + hi) ^ sw5)) * 8);
            __builtin_amdgcn_s_setprio(1);
            sfrA = __builtin_amdgcn_mfma_f32_32x32x16_bf16(a0, qf[0], z16, 0, 0, 0);
            sfrB = __builtin_amdgcn_mfma_f32_32x32x16_bf16(b0, qf[0], z16, 0, 0, 0);
            sfrA = __builtin_amdgcn_mfma_f32_32x32x16_bf16(a1, qf[1], sfrA, 0, 0, 0);
            sfrB = __builtin_amdgcn_mfma_f32_32x32x16_bf16(b1, qf[1], sfrB, 0, 0, 0);
            sfrA = __builtin_amdgcn_mfma_f32_32x32x16_bf16(a2, qf[2], sfrA, 0, 0, 0);
            sfrB = __builtin_amdgcn_mfma_f32_32x32x16_bf16(b2, qf[2], sfrB, 0, 0, 0);
            sfrA = __builtin_amdgcn_mfma_f32_32x32x16_bf16(a3, qf[3], sfrA, 0, 0, 0);
            sfrB = __builtin_amdgcn_mfma_f32_32x32x16_bf16(b3, qf[3], sfrB, 0, 0, 0);
            __builtin_amdgcn_s_setprio(0);
        }

        // ---- stream A: exp2 -> lsum -> pack -> swap -> PV ----
        {
            float p[16];
#pragma unroll
            for (int r = 0; r < 16; ++r) p[r] = __builtin_amdgcn_exp2f(sfrA[r]);
            const float s0 = (p[0] + p[1]) + (p[2] + p[3]);
            const float s1 = (p[4] + p[5]) + (p[6] + p[7]);
            const float s2 = (p[8] + p[9]) + (p[10] + p[11]);
            const float s3 = (p[12] + p[13]) + (p[14] + p[15]);
            lsum += (s0 + s1) + (s2 + s3);
            const u32 W00 = cvtpk_bf16(p[0], p[1]);
            const u32 W01 = cvtpk_bf16(p[2], p[3]);
            const u32 W10 = cvtpk_bf16(p[4], p[5]);
            const u32 W11 = cvtpk_bf16(p[6], p[7]);
            const u32 W20 = cvtpk_bf16(p[8], p[9]);
            const u32 W21 = cvtpk_bf16(p[10], p[11]);
            const u32 W30 = cvtpk_bf16(p[12], p[13]);
            const u32 W31 = cvtpk_bf16(p[14], p[15]);
            const u32x2 e0 = __builtin_amdgcn_permlane32_swap(W00, W10, false, false);
            const u32x2 e1 = __builtin_amdgcn_permlane32_swap(W01, W11, false, false);
            const u32x2 e2 = __builtin_amdgcn_permlane32_swap(W20, W30, false, false);
            const u32x2 e3 = __builtin_amdgcn_permlane32_swap(W21, W31, false, false);
            u32x4 A0 = { e0[0], e1[0], e0[1], e1[1] };
            u32x4 A1 = { e2[0], e3[0], e2[1], e3[1] };
            const bf16x8 pa0 = *(const bf16x8*)&A0;
            const bf16x8 pa1 = *(const bf16x8*)&A1;
            const bf16x8 v00 = *(const bf16x8*)(sVA + l31 * 64 + (((0 + hi) ^ sw5)) * 8);
            const bf16x8 v01 = *(const bf16x8*)(sVA + l31 * 64 + (((2 + hi) ^ sw5)) * 8);
            const bf16x8 v10 = *(const bf16x8*)(sVA + l31 * 64 + (((4 + hi) ^ sw5)) * 8);
            const bf16x8 v11 = *(const bf16x8*)(sVA + l31 * 64 + (((6 + hi) ^ sw5)) * 8);
            __builtin_amdgcn_s_setprio(1);
            oc[0] = __builtin_amdgcn_mfma_f32_32x32x16_bf16(pa0, v00, oc[0], 0, 0, 0);
            oc[1] = __builtin_amdgcn_mfma_f32_32x32x16_bf16(pa0, v10, oc[1], 0, 0, 0);
            oc[0] = __builtin_amdgcn_mfma_f32_32x32x16_bf16(pa1, v01, oc[0], 0, 0, 0);
            oc[1] = __builtin_amdgcn_mfma_f32_32x32x16_bf16(pa1, v11, oc[1], 0, 0, 0);
            __builtin_amdgcn_s_setprio(0);
        }

        // ---- stream B: exp2 -> lsum -> pack -> swap -> PV ----
        {
            float p[16];
#pragma unroll
            for (int r = 0; r < 16; ++r) p[r] = __builtin_amdgcn_exp2f(sfrB[r]);
            const float s0 = (p[0] + p[1]) + (p[2] + p[3]);
            const float s1 = (p[4] + p[5]) + (p[6] + p[7]);
            const float s2 = (p[8] + p[9]) + (p[10] + p[11]);
            const float s3 = (p[12] + p[13]) + (p[14] + p[15]);
            lsum += (s0 + s1) + (s2 + s3);
            const u32 W00 = cvtpk_bf16(p[0], p[1]);
            const u32 W01 = cvtpk_bf16(p[2], p[3]);
            const u32 W10 = cvtpk_bf16(p[4], p[5]);
            const u32 W11 = cvtpk_bf16(p[6], p[7]);
            const u32 W20 = cvtpk_bf16(p[8], p[9]);
            const u32 W21 = cvtpk_bf16(p[10], p[11]);
            const u32 W30 = cvtpk_bf16(p[12], p[13]);
            const u32 W31 = cvtpk_bf16(p[14], p[15]);
            const u32x2 e0 = __builtin_amdgcn_permlane32_swap(W00, W10, false, false);
            const u32x2 e1 = __builtin_amdgcn_permlane32_swap(W01, W11, false, false);
            const u32x2 e2 = __builtin_amdgcn_permlane32_swap(W20, W30, false, false);
            const u32x2 e3 = __builtin_amdgcn_permlane32_swap(W21, W31, false, false);
            u32x4 A0 = { e0[0], e1[0], e0[1], e1[1] };
            u32x4 A1 = { e2[0], e3[0], e2[1], e3[1] };
            const bf16x8 pa0 = *(const bf16x8*)&A0;
            const bf16x8 pa1 = *(const bf16x8*)&A1;
            const bf16x8 v00 = *(const bf16x8*)(sVB + l31 * 64 + (((0 + hi) ^ sw5)) * 8);
            const bf16x8 v01 = *(const bf16x8*)(sVB + l31 * 64 + (((2 + hi) ^ sw5)) * 8);
            const bf16x8 v10 = *(const bf16x8*)(sVB + l31 * 64 + (((4 + hi) ^ sw5)) * 8);
            const bf16x8 v11 = *(const bf16x8*)(sVB + l31 * 64 + (((6 + hi) ^ sw5)) * 8);
            __builtin_amdgcn_s_setprio(1);
            oc[0] = __builtin_amdgcn_mfma_f32_32x32x16_bf16(pa0, v00, oc[0], 0, 0, 0);
            oc[1] = __builtin_amdgcn_mfma_f32_32x32x16_bf16(pa0, v10, oc[1], 0, 0, 0);
            oc[0] = __builtin_amdgcn_mfma_f32_32x32x16_bf16(pa1, v01, oc[0], 0, 0, 0);
            oc[1] = __builtin_amdgcn_mfma_f32_32x32x16_bf16(pa1, v11, oc[1], 0, 0, 0);
            __builtin_amdgcn_s_setprio(0);
        }
    }

    // complete lsum across the two lane-halves: one swap, then select partner
    {
        union { float f; u32 u; } lu; lu.f = lsum;
        const u32x2 lr2 = __builtin_amdgcn_permlane32_swap(lu.u, lu.u, false, false);
        union { u32 u; float f; } pu; pu.u = hi ? lr2[0] : lr2[1];
        lsum += pu.f;
    }

    // ---- merge the two KV-groups' partial sums via LDS ----
    __syncthreads();                    // all compute done; KV regions dead
    float* sO = (float*)&sKV[0][0][0];  // 32KB: [qg][2048] f32 partial O (kg=1)
    float* sL = (float*)((char*)sO + 32768);   // [kg][128] lsums
    if (hi == 0) sL[kg * 128 + qg * 32 + l31] = lsum;
    if (kg == 1) {
#pragma unroll
        for (int dh = 0; dh < 2; ++dh)
#pragma unroll
            for (int g = 0; g < 4; ++g) {
                f32x4 t = { oc[dh][g * 4 + 0], oc[dh][g * 4 + 1],
                            oc[dh][g * 4 + 2], oc[dh][g * 4 + 3] };
                *(f32x4*)(sO + qg * 2048 + ((dh * 4 + g) * 2 + hi) * 128 + l31 * 4) = t;
            }
    }
    __syncthreads();
    if (kg == 0) {
        const float nm = nmaskf[b];
#pragma unroll
        for (int g = 0; g < 4; ++g) {
            const f32x4 oA = *(const f32x4*)(sO + qg * 2048 + ((0 + g) * 2 + hi) * 128 + l31 * 4);
            const f32x4 oB = *(const f32x4*)(sO + qg * 2048 + ((4 + g) * 2 + hi) * 128 + l31 * 4);
#pragma unroll
            for (int rr = 0; rr < 4; ++rr) {
                const int qrow = rr + 8 * g + 4 * hi;   // (r&3)+8*(r>>2)+4*hi
                const float inv = __builtin_amdgcn_rcpf(
                    sL[qg * 32 + qrow] + sL[128 + qg * 32 + qrow] - nm);
                const int s = qt * 128 + qg * 32 + qrow;
                const size_t base = ((size_t)(b * S_ + s)) * D_ + h * 64 + l31;
                Xc[base]      = f2bf((oc[0][g * 4 + rr] + oA[rr]) * inv);
                Xc[base + 32] = f2bf((oc[1][g * 4 + rr] + oB[rr]) * inv);
            }
        }
    }
}

// ---------------------------------------------------------------------------
extern "C" void kernel_launch(void* const* d_in, const int* in_sizes, int n_in,
                              void* d_out, int out_size, void* d_ws, size_t ws_size,
                              hipStream_t stream)
{
    (void)in_sizes; (void)n_in; (void)out_size; (void)ws_size;

    const float* query = (const float*)d_in[0];
    const float* key   = (const float*)d_in[1];
    const float* value = (const float*)d_in[2];
    const int*   mask  = (const int*)d_in[3];
    const float* wq    = (const float*)d_in[4];
    const float* bq    = (const float*)d_in[5];
    const float* wk    = (const float*)d_in[6];
    const float* bk    = (const float*)d_in[7];
    const float* wv    = (const float*)d_in[8];
    const float* bv    = (const float*)d_in[9];
    const float* wo    = (const float*)d_in[10];
    const float* bo    = (const float*)d_in[11];

    const size_t NE = (size_t)B_ * S_ * D_;   // 4,194,304
    const size_t WE = (size_t)D_ * D_;        // 1,048,576

    u16* qb  = (u16*)d_ws;      // bf16 inputs
    u16* kb  = qb + NE;
    u16* vb  = kb + NE;
    u16* wqb = vb + NE;         // bf16 weights
    u16* wkb = wqb + WE;
    u16* wvb = wkb + WE;
    u16* wob = wvb + WE;
    u16* Qp  = wob + WE;        // projected heads
    u16* Kp  = Qp + NE;
    u16* Vt  = Kp + NE;         // V transposed: [h*64+dk][b*2048+s]
    float* mfac   = (float*)(Vt + NE);   // 4096 f32 mask factors (1/0)
    float* nmaskf = mfac + 4096;         // 2 f32 masked-key counts
    u16* Xc  = qb;              // alias: qb is dead after qkv_gemm

    cast_all<<<2066, 256, 0, stream>>>(query, key, value, wq, wk, wv, wo, mask,
                                       qb, kb, vb, wqb, wkb, wvb, wob, mfac, nmaskf);

    qkv_gemm<<<768, 256, 0, stream>>>(
        qb, kb, vb, wqb, wkb, wvb, bq, bk, bv, Qp, Kp, Vt, mfac);

    attn_mfma<<<512, 512, 0, stream>>>(Qp, Kp, Vt, nmaskf, Xc);

    out_gemm<<<512, 256, 0, stream>>>(Xc, wob, bo, (float*)d_out);
}

// Round 8
// 211.079 us; speedup vs baseline: 1.0614x; 1.0614x over previous
//
#include <hip/hip_runtime.h>
#include <math.h>

#define B_  2
#define S_  2048
#define D_  1024
#define H_  16
#define DK_ 64

typedef unsigned short u16;
typedef unsigned int u32;
typedef __bf16 bf16x8 __attribute__((ext_vector_type(8)));
typedef float f32x4 __attribute__((ext_vector_type(4)));
typedef float f32x16 __attribute__((ext_vector_type(16)));
typedef u32 u32x2 __attribute__((ext_vector_type(2)));
typedef u32 u32x4 __attribute__((ext_vector_type(4)));

typedef const __attribute__((address_space(1))) void* gas1_t;
typedef __attribute__((address_space(3))) void* las3_t;

__device__ __forceinline__ void gload_lds16(const void* g, void* l) {
    // async global->LDS, 16B per lane; LDS dst = wave-uniform base + lane*16
    __builtin_amdgcn_global_load_lds((gas1_t)g, (las3_t)l, 16, 0, 0);
}

__device__ __forceinline__ u16 f2bf(float f) {
    union { float f; unsigned u; } v; v.f = f;
    return (u16)((v.u + 0x7fffu + ((v.u >> 16) & 1u)) >> 16);   // RNE
}

// pack two f32 into two bf16 (RNE-ish round-half-up) in one u32: [lo | hi<<16]
__device__ __forceinline__ u32 pack_bf16_2(float lo, float hi) {
    union { float f; u32 u; } a, b;
    a.f = lo; b.f = hi;
    return __builtin_amdgcn_perm(b.u + 0x8000u, a.u + 0x8000u, 0x07060302u);
}

// single-instruction packed f32->bf16 (RNE), lo = src0, hi = src1
__device__ __forceinline__ u32 cvtpk_bf16(float lo, float hi) {
    u32 r;
    asm("v_cvt_pk_bf16_f32 %0, %1, %2" : "=v"(r) : "v"(lo), "v"(hi));
    return r;
}

// ---------------------------------------------------------------------------
// Fused fp32 -> bf16 cast over all 7 tensors + mask -> f32 factor (1 / 0)
// + per-batch masked-key count (softmax denominator correction).
// grid-stride (G11): 2048 tensor blocks x 8 float4/thread + 16 + 2.
// ---------------------------------------------------------------------------
__global__ __launch_bounds__(256)
void cast_all(const float* __restrict__ q, const float* __restrict__ k,
              const float* __restrict__ v, const float* __restrict__ wq,
              const float* __restrict__ wk, const float* __restrict__ wv,
              const float* __restrict__ wo, const int* __restrict__ mask,
              u16* __restrict__ qb, u16* __restrict__ kb, u16* __restrict__ vb,
              u16* __restrict__ wqb, u16* __restrict__ wkb, u16* __restrict__ wvb,
              u16* __restrict__ wob, float* __restrict__ mfac,
              float* __restrict__ nmaskf)
{
    const int bi = blockIdx.x;
    const int tid = threadIdx.x;
    if (bi >= 2064) {                  // masked-key count for batch b
        const int b = bi - 2064;
        __shared__ int red[256];
        int c = 0;
#pragma unroll
        for (int j = 0; j < 8; ++j)
            c += (mask[b * S_ + tid * 8 + j] == 0) ? 1 : 0;
        red[tid] = c;
        __syncthreads();
        for (int s = 128; s > 0; s >>= 1) {
            if (tid < s) red[tid] += red[tid + s];
            __syncthreads();
        }
        if (tid == 0) nmaskf[b] = (float)red[0];
        return;
    }
    if (bi >= 2048) {                  // mask -> float factor
        const int idx = (bi - 2048) * 256 + tid;
        mfac[idx] = mask[idx] ? 1.0f : 0.0f;
        return;
    }
#pragma unroll
    for (int j = 0; j < 8; ++j) {
        const int i = bi * 256 + tid + j * 524288;     // float4 index
        const float* src; u16* dst; int off;
        if (i < 3 * 1048576) {
            const int seg = i >> 20; off = i & 1048575;
            src = (seg == 0) ? q : (seg == 1) ? k : v;
            dst = (seg == 0) ? qb : (seg == 1) ? kb : vb;
        } else {
            const int jj = i - 3 * 1048576;
            const int seg = jj >> 18; off = jj & 262143;
            src = (seg == 0) ? wq : (seg == 1) ? wk : (seg == 2) ? wv : wo;
            dst = (seg == 0) ? wqb : (seg == 1) ? wkb : (seg == 2) ? wvb : wob;
        }
        const float4 val = ((const float4*)src)[off];
        uint2 o;
        o.x = pack_bf16_2(val.x, val.y);
        o.y = pack_bf16_2(val.z, val.w);
        ((uint2*)dst)[off] = o;
    }
}

// ---------------------------------------------------------------------------
// bf16 NT GEMM, BK=64, XOR-swizzled LDS (16B chunks, chunk ^= row&7) so
// fragment ds_read_b128 are conflict-free. 4 waves in 2x2. 16 K-iters.
// R8: back to single-buffer (R7's dbuf cost occupancy for nothing: kernel
// is TLP-bound, not staging-latency bound) + BM templated to 64 so qkv
// runs 1536 blocks @ 24KB LDS = 6 blocks/CU (24 waves/CU, was 12).
// mode 0: fp32 out[m*D+n], bias[n]
// mode 1: bf16 out[((b*H+h)*S+s)*DK+dk] (split heads), bias[n], *scale,
//         optionally * rowfac[m]   (K projection: zero masked key rows)
// mode 3: bf16 out[m*4096+n], bias[m], optionally * colfac[n]  (V^T)
// ---------------------------------------------------------------------------
template<int BM, int BN>
__device__ __forceinline__ void gemm_body(
    const u16* __restrict__ A, const u16* __restrict__ W,
    const float* __restrict__ bias, void* __restrict__ outp,
    float scale, int mode, int m0, int n0,
    const float* __restrict__ rowfac, const float* __restrict__ colfac)
{
    constexpr int MI = BM / 32;       // i-tiles per wave (rows/16 per half)
    constexpr int NJ = BN / 32;       // j-tiles per wave
    __shared__ u16 sA[BM * 64];       // BM*128 bytes
    __shared__ u16 sW[BN * 64];

    const int tid  = threadIdx.x;
    const int wave = tid >> 6, lane = tid & 63;
    const int quad = lane >> 4, l16 = lane & 15;
    const int wm = (wave >> 1) * (BM / 2);
    const int wn = (wave & 1) * (BN / 2);
    const int srow = lane >> 3;                 // row within 8-row staging group
    const int scol = ((lane & 7) ^ srow) * 8;   // swizzled source column (u16)
    const int sw7  = l16 & 7;

    f32x4 acc[MI][NJ];
    const f32x4 zero = {0.f, 0.f, 0.f, 0.f};
#pragma unroll
    for (int i = 0; i < MI; ++i)
#pragma unroll
        for (int j = 0; j < NJ; ++j) acc[i][j] = zero;

    const u16* ast = A + (size_t)(m0 + wave * 8 + srow) * D_ + scol;
    const u16* wst = W + (size_t)(n0 + wave * 8 + srow) * D_ + scol;

    for (int k0 = 0; k0 < D_; k0 += 64) {
#pragma unroll
        for (int t = 0; t < BM / 32; ++t)
            gload_lds16(ast + (size_t)t * 32 * D_ + k0, sA + (wave + t * 4) * 512);
#pragma unroll
        for (int t = 0; t < BN / 32; ++t)
            gload_lds16(wst + (size_t)t * 32 * D_ + k0, sW + (wave + t * 4) * 512);
        __syncthreads();

#pragma unroll
        for (int kh = 0; kh < 2; ++kh) {
            const int phys = ((kh * 4 + quad) ^ sw7) * 8;
            bf16x8 af[MI], bfr[NJ];
#pragma unroll
            for (int i = 0; i < MI; ++i)
                af[i] = *(const bf16x8*)(sA + (wm + i * 16 + l16) * 64 + phys);
#pragma unroll
            for (int j = 0; j < NJ; ++j)
                bfr[j] = *(const bf16x8*)(sW + (wn + j * 16 + l16) * 64 + phys);
#pragma unroll
            for (int i = 0; i < MI; ++i)
#pragma unroll
                for (int j = 0; j < NJ; ++j)
                    acc[i][j] = __builtin_amdgcn_mfma_f32_16x16x32_bf16(af[i], bfr[j], acc[i][j], 0, 0, 0);
        }
        __syncthreads();
    }

    // Epilogue. C frag: row = quad*4+reg, col = lane&15
#pragma unroll
    for (int i = 0; i < MI; ++i) {
        float rf4[4];
        if (mode == 1 && rowfac) {
#pragma unroll
            for (int r = 0; r < 4; ++r)
                rf4[r] = rowfac[m0 + wm + i * 16 + quad * 4 + r];
        }
#pragma unroll
        for (int j = 0; j < NJ; ++j) {
            const int n = n0 + wn + j * 16 + l16;
            if (mode == 3) {
                const float cf = colfac ? colfac[n] : 1.0f;
#pragma unroll
                for (int r = 0; r < 4; ++r) {
                    const int mp = m0 + wm + i * 16 + quad * 4 + r;
                    ((u16*)outp)[(size_t)mp * (B_ * S_) + n] = f2bf((acc[i][j][r] + bias[mp]) * cf);
                }
            } else {
                const float bn = bias[n];
#pragma unroll
                for (int r = 0; r < 4; ++r) {
                    const int m = m0 + wm + i * 16 + quad * 4 + r;
                    float v = acc[i][j][r] + bn;
                    if (mode == 0) {
                        ((float*)outp)[(size_t)m * D_ + n] = v;
                    } else {
                        v *= scale;
                        if (rowfac) v *= rf4[r];
                        const int b = m >> 11, s = m & (S_ - 1);
                        const int h = n >> 6, dk = n & 63;
                        ((u16*)outp)[(((size_t)(b * H_ + h)) * S_ + s) * DK_ + dk] = f2bf(v);
                    }
                }
            }
        }
    }
}

// R8: 1536 blocks (3 x 512), BM=64 tiles, bijective chunked XCD swizzle:
// XCD k gets a contiguous 192-block chunk -> W panels stay L2-resident,
// A panels fetched ~once (R7 measured: FETCH 101.6 -> 29.8 MB).
__global__ __launch_bounds__(256)
void qkv_gemm(const u16* __restrict__ qin, const u16* __restrict__ kin, const u16* __restrict__ vin,
              const u16* __restrict__ wqb, const u16* __restrict__ wkb, const u16* __restrict__ wvb,
              const float* __restrict__ bq, const float* __restrict__ bk, const float* __restrict__ bv,
              u16* __restrict__ Qp, u16* __restrict__ Kp, u16* __restrict__ Vt,
              const float* __restrict__ mfac)
{
    const int bid = blockIdx.x;                      // 1536 blocks
    const int swz = (bid & 7) * 192 + (bid >> 3);    // 1536 = 8 * 192, bijective
    const int z   = swz >> 9;                        // 3 slices of 512
    const int rem = swz & 511;

    if (z == 2) {
        // V^T = Wv . value^T ; zero masked key columns via colfac
        // A = wvb (1024 rows -> 16 x 64), W = vin (4096 rows -> 32 x 128)
        const int mi = rem & 15, ni = rem >> 4;
        gemm_body<64, 128>(wvb, vin, bv, Vt, 1.0f, 3, mi * 64, ni * 128,
                           nullptr, mfac);
    } else {
        const int by = rem >> 3;                     // 0..63 (64-row A tile)
        const int bx = rem & 7;                      // 0..7  (128-row W tile)
        const u16* A = (z == 0) ? qin : kin;
        const u16* W = (z == 0) ? wqb : wkb;
        const float* bias = (z == 0) ? bq : bk;
        u16* outp = (z == 0) ? Qp : Kp;
        // Q pre-scaled by log2(e)/sqrt(DK); K rows zeroed where masked
        const float scale = (z == 0) ? 0.18033688011112042f : 1.0f;
        const float* rf = (z == 1) ? mfac : nullptr;
        gemm_body<64, 128>(A, W, bias, outp, scale, 1, by * 64, bx * 128,
                           rf, nullptr);
    }
}

__global__ __launch_bounds__(256)
void out_gemm(const u16* __restrict__ Xc, const u16* __restrict__ wob,
              const float* __restrict__ bo, float* __restrict__ out)
{
    const int bid = blockIdx.x;                      // 1024 blocks
    const int swz = (bid & 7) * 128 + (bid >> 3);    // 1024 = 8 * 128, bijective
    const int by  = swz >> 4;                        // 0..63 (64-row Xc tile)
    const int bx  = swz & 15;                        // 0..15 (64-col W tile)
    gemm_body<64, 64>(Xc, wob, bo, out, 1.0f, 0, by * 64, bx * 64,
                      nullptr, nullptr);
}

// ---------------------------------------------------------------------------
// MFMA flash attention, S^T orientation, fixed-shift exp2 softmax, maskless.
//
// R5 structure (two independent 32-key streams/iter, Q in registers,
// permlane32_swap P exchange, cvt_pk pack) + chunked XCD swizzle.
// ---------------------------------------------------------------------------
__global__ __launch_bounds__(512, 4)
void attn_mfma(const u16* __restrict__ Qp, const u16* __restrict__ Kp,
               const u16* __restrict__ Vt, const float* __restrict__ nmaskf,
               u16* __restrict__ Xc)
{
    __shared__ u16 sKV[2][2][8192];  // [kg][buf][K0|K1|V0|V1] 64KB;
                                     // epilogue overlay: sO 32KB + sL 1KB

    const int tid  = threadIdx.x;
    const int wave = tid >> 6, lane = tid & 63;
    const int qg = wave & 3, kg = wave >> 2;
    const int l31 = lane & 31, hi = lane >> 5;
    const int bid = blockIdx.x;                      // 512 blocks
    const int swz = (bid & 7) * 64 + (bid >> 3);     // bijective chunk swizzle
    const int qt = swz & 15;
    const int bh = swz >> 4;
    const int b  = bh >> 4;
    const int h  = bh & 15;
    const int lr  = lane >> 3;          // staging row within 8-row group
    const int cl  = (lane & 7) ^ lr;    // logical chunk for pre-swizzled source
    const int sw5 = l31 & 7;            // row&7 for fragment reads

    const u16* Qb = Qp + ((size_t)bh * S_ + qt * 128) * DK_;
    const u16* Kb = Kp + (size_t)bh * S_ * DK_;
    // V staging: interleaved layout, physical row pr = qg*8+lr holds
    // dk = pr + 32*(cl>>2), key-chunk (cl&3)*8 of a 32-key sub-tile.
    const int vdk = (qg * 8 + lr) + 32 * (cl >> 2);
    const u16* Vsrc = Vt + (size_t)(h * 64 + vdk) * (B_ * S_) + b * S_ + (cl & 3) * 8;
    const u16* Ksrc = Kb + (size_t)(qg * 8 + lr) * DK_ + cl * 8;

    // Q straight to registers (no LDS): qf[ks] = Q[qg*32+l31][ks*16+hi*8+..8]
    bf16x8 qf[4];
    {
        const u16* qrow = Qb + (size_t)(qg * 32 + l31) * DK_ + hi * 8;
        qf[0] = *(const bf16x8*)(qrow);
        qf[1] = *(const bf16x8*)(qrow + 16);
        qf[2] = *(const bf16x8*)(qrow + 32);
        qf[3] = *(const bf16x8*)(qrow + 48);
    }

    // stage first 64-key chunk (c0 = kg): K sub0/sub1 + V sub0/sub1
    const u16* kpre = Ksrc + (size_t)kg * 64 * DK_;
    const u16* vpre = Vsrc + kg * 64;
    {
        u16* dst = sKV[kg][0];
        gload_lds16(kpre,                    dst + qg * 512);
        gload_lds16(kpre + (size_t)32 * DK_, dst + 2048 + qg * 512);
        gload_lds16(vpre,                    dst + 4096 + qg * 512);
        gload_lds16(vpre + 32,               dst + 6144 + qg * 512);
        kpre += (size_t)128 * DK_;
        vpre += 128;
    }

    f32x16 oc[2];                   // [dhalf]: col dk = dh*32+l31, rows q(reg,hi)
    const f32x16 z16 = {0.f,0.f,0.f,0.f,0.f,0.f,0.f,0.f,
                        0.f,0.f,0.f,0.f,0.f,0.f,0.f,0.f};
    oc[0] = z16; oc[1] = z16;
    float lsum = 0.f;               // partial row sum (own 16 keys per stream)

    for (int i = 0; i < 16; ++i) {      // group kg: 64-key chunk c = 2*i+kg
        __syncthreads();                // cur buf staged; prev iter's reads done
        const int cur = i & 1;

        // issue next chunk's staging NOW (async, drains at next top barrier)
        if (i < 15) {
            u16* dst = sKV[kg][cur ^ 1];
            gload_lds16(kpre,                    dst + qg * 512);
            gload_lds16(kpre + (size_t)32 * DK_, dst + 2048 + qg * 512);
            gload_lds16(vpre,                    dst + 4096 + qg * 512);
            gload_lds16(vpre + 32,               dst + 6144 + qg * 512);
            kpre += (size_t)128 * DK_;
            vpre += 128;
        }
        const u16* sKA = sKV[kg][cur];
        const u16* sKB = sKA + 2048;
        const u16* sVA = sKA + 4096;
        const u16* sVB = sKA + 6144;

        // ---- S^T for BOTH streams (independent 4-MFMA chains) ----
        f32x16 sfrA, sfrB;
        {
            const bf16x8 a0 = *(const bf16x8*)(sKA + l31 * 64 + (((0 + hi) ^ sw5)) * 8);
            const bf16x8 a1 = *(const bf16x8*)(sKA + l31 * 64 + (((2 + hi) ^ sw5)) * 8);
            const bf16x8 a2 = *(const bf16x8*)(sKA + l31 * 64 + (((4 + hi) ^ sw5)) * 8);
            const bf16x8 a3 = *(const bf16x8*)(sKA + l31 * 64 + (((6 + hi) ^ sw5)) * 8);
            const bf16x8 b0 = *(const bf16x8*)(sKB + l31 * 64 + (((0 + hi) ^ sw5)) * 8);
            const bf16x8 b1 = *(const bf16x8*)(sKB + l31 * 64 + (((2 + hi) ^ sw5)) * 8);
            const bf16x8 b2 = *(const bf16x8*)(sKB + l31 * 64 + (((4 + hi) ^ sw5)) * 8);
            const bf16x8 b3 = *(const bf16x8*)(sKB + l31 * 64 + (((6 + hi) ^ sw5)) * 8);
            __builtin_amdgcn_s_setprio(1);
            sfrA = __builtin_amdgcn_mfma_f32_32x32x16_bf16(a0, qf[0], z16, 0, 0, 0);
            sfrB = __builtin_amdgcn_mfma_f32_32x32x16_bf16(b0, qf[0], z16, 0, 0, 0);
            sfrA = __builtin_amdgcn_mfma_f32_32x32x16_bf16(a1, qf[1], sfrA, 0, 0, 0);
            sfrB = __builtin_amdgcn_mfma_f32_32x32x16_bf16(b1, qf[1], sfrB, 0, 0, 0);
            sfrA = __builtin_amdgcn_mfma_f32_32x32x16_bf16(a2, qf[2], sfrA, 0, 0, 0);
            sfrB = __builtin_amdgcn_mfma_f32_32x32x16_bf16(b2, qf[2], sfrB, 0, 0, 0);
            sfrA = __builtin_amdgcn_mfma_f32_32x32x16_bf16(a3, qf[3], sfrA, 0, 0, 0);
            sfrB = __builtin_amdgcn_mfma_f32_32x32x16_bf16(b3, qf[3], sfrB, 0, 0, 0);
            __builtin_amdgcn_s_setprio(0);
        }

        // ---- stream A: exp2 -> lsum -> pack -> swap -> PV ----
        {
            float p[16];
#pragma unroll
            for (int r = 0; r < 16; ++r) p[r] = __builtin_amdgcn_exp2f(sfrA[r]);
            const float s0 = (p[0] + p[1]) + (p[2] + p[3]);
            const float s1 = (p[4] + p[5]) + (p[6] + p[7]);
            const float s2 = (p[8] + p[9]) + (p[10] + p[11]);
            const float s3 = (p[12] + p[13]) + (p[14] + p[15]);
            lsum += (s0 + s1) + (s2 + s3);
            const u32 W00 = cvtpk_bf16(p[0], p[1]);
            const u32 W01 = cvtpk_bf16(p[2], p[3]);
            const u32 W10 = cvtpk_bf16(p[4], p[5]);
            const u32 W11 = cvtpk_bf16(p[6], p[7]);
            const u32 W20 = cvtpk_bf16(p[8], p[9]);
            const u32 W21 = cvtpk_bf16(p[10], p[11]);
            const u32 W30 = cvtpk_bf16(p[12], p[13]);
            const u32 W31 = cvtpk_bf16(p[14], p[15]);
            const u32x2 e0 = __builtin_amdgcn_permlane32_swap(W00, W10, false, false);
            const u32x2 e1 = __builtin_amdgcn_permlane32_swap(W01, W11, false, false);
            const u32x2 e2 = __builtin_amdgcn_permlane32_swap(W20, W30, false, false);
            const u32x2 e3 = __builtin_amdgcn_permlane32_swap(W21, W31, false, false);
            u32x4 A0 = { e0[0], e1[0], e0[1], e1[1] };
            u32x4 A1 = { e2[0], e3[0], e2[1], e3[1] };
            const bf16x8 pa0 = *(const bf16x8*)&A0;
            const bf16x8 pa1 = *(const bf16x8*)&A1;
            const bf16x8 v00 = *(const bf16x8*)(sVA + l31 * 64 + (((0 + hi) ^ sw5)) * 8);
            const bf16x8 v01 = *(const bf16x8*)(sVA + l31 * 64 + (((2 + hi) ^ sw5)) * 8);
            const bf16x8 v10 = *(const bf16x8*)(sVA + l31 * 64 + (((4 + hi) ^ sw5)) * 8);
            const bf16x8 v11 = *(const bf16x8*)(sVA + l31 * 64 + (((6 + hi) ^ sw5)) * 8);
            __builtin_amdgcn_s_setprio(1);
            oc[0] = __builtin_amdgcn_mfma_f32_32x32x16_bf16(pa0, v00, oc[0], 0, 0, 0);
            oc[1] = __builtin_amdgcn_mfma_f32_32x32x16_bf16(pa0, v10, oc[1], 0, 0, 0);
            oc[0] = __builtin_amdgcn_mfma_f32_32x32x16_bf16(pa1, v01, oc[0], 0, 0, 0);
            oc[1] = __builtin_amdgcn_mfma_f32_32x32x16_bf16(pa1, v11, oc[1], 0, 0, 0);
            __builtin_amdgcn_s_setprio(0);
        }

        // ---- stream B: exp2 -> lsum -> pack -> swap -> PV ----
        {
            float p[16];
#pragma unroll
            for (int r = 0; r < 16; ++r) p[r] = __builtin_amdgcn_exp2f(sfrB[r]);
            const float s0 = (p[0] + p[1]) + (p[2] + p[3]);
            const float s1 = (p[4] + p[5]) + (p[6] + p[7]);
            const float s2 = (p[8] + p[9]) + (p[10] + p[11]);
            const float s3 = (p[12] + p[13]) + (p[14] + p[15]);
            lsum += (s0 + s1) + (s2 + s3);
            const u32 W00 = cvtpk_bf16(p[0], p[1]);
            const u32 W01 = cvtpk_bf16(p[2], p[3]);
            const u32 W10 = cvtpk_bf16(p[4], p[5]);
            const u32 W11 = cvtpk_bf16(p[6], p[7]);
            const u32 W20 = cvtpk_bf16(p[8], p[9]);
            const u32 W21 = cvtpk_bf16(p[10], p[11]);
            const u32 W30 = cvtpk_bf16(p[12], p[13]);
            const u32 W31 = cvtpk_bf16(p[14], p[15]);
            const u32x2 e0 = __builtin_amdgcn_permlane32_swap(W00, W10, false, false);
            const u32x2 e1 = __builtin_amdgcn_permlane32_swap(W01, W11, false, false);
            const u32x2 e2 = __builtin_amdgcn_permlane32_swap(W20, W30, false, false);
            const u32x2 e3 = __builtin_amdgcn_permlane32_swap(W21, W31, false, false);
            u32x4 A0 = { e0[0], e1[0], e0[1], e1[1] };
            u32x4 A1 = { e2[0], e3[0], e2[1], e3[1] };
            const bf16x8 pa0 = *(const bf16x8*)&A0;
            const bf16x8 pa1 = *(const bf16x8*)&A1;
            const bf16x8 v00 = *(const bf16x8*)(sVB + l31 * 64 + (((0 + hi) ^ sw5)) * 8);
            const bf16x8 v01 = *(const bf16x8*)(sVB + l31 * 64 + (((2 + hi) ^ sw5)) * 8);
            const bf16x8 v10 = *(const bf16x8*)(sVB + l31 * 64 + (((4 + hi) ^ sw5)) * 8);
            const bf16x8 v11 = *(const bf16x8*)(sVB + l31 * 64 + (((6 + hi) ^ sw5)) * 8);
            __builtin_amdgcn_s_setprio(1);
            oc[0] = __builtin_amdgcn_mfma_f32_32x32x16_bf16(pa0, v00, oc[0], 0, 0, 0);
            oc[1] = __builtin_amdgcn_mfma_f32_32x32x16_bf16(pa0, v10, oc[1], 0, 0, 0);
            oc[0] = __builtin_amdgcn_mfma_f32_32x32x16_bf16(pa1, v01, oc[0], 0, 0, 0);
            oc[1] = __builtin_amdgcn_mfma_f32_32x32x16_bf16(pa1, v11, oc[1], 0, 0, 0);
            __builtin_amdgcn_s_setprio(0);
        }
    }

    // complete lsum across the two lane-halves: one swap, then select partner
    {
        union { float f; u32 u; } lu; lu.f = lsum;
        const u32x2 lr2 = __builtin_amdgcn_permlane32_swap(lu.u, lu.u, false, false);
        union { u32 u; float f; } pu; pu.u = hi ? lr2[0] : lr2[1];
        lsum += pu.f;
    }

    // ---- merge the two KV-groups' partial sums via LDS ----
    __syncthreads();                    // all compute done; KV regions dead
    float* sO = (float*)&sKV[0][0][0];  // 32KB: [qg][2048] f32 partial O (kg=1)
    float* sL = (float*)((char*)sO + 32768);   // [kg][128] lsums
    if (hi == 0) sL[kg * 128 + qg * 32 + l31] = lsum;
    if (kg == 1) {
#pragma unroll
        for (int dh = 0; dh < 2; ++dh)
#pragma unroll
            for (int g = 0; g < 4; ++g) {
                f32x4 t = { oc[dh][g * 4 + 0], oc[dh][g * 4 + 1],
                            oc[dh][g * 4 + 2], oc[dh][g * 4 + 3] };
                *(f32x4*)(sO + qg * 2048 + ((dh * 4 + g) * 2 + hi) * 128 + l31 * 4) = t;
            }
    }
    __syncthreads();
    if (kg == 0) {
        const float nm = nmaskf[b];
#pragma unroll
        for (int g = 0; g < 4; ++g) {
            const f32x4 oA = *(const f32x4*)(sO + qg * 2048 + ((0 + g) * 2 + hi) * 128 + l31 * 4);
            const f32x4 oB = *(const f32x4*)(sO + qg * 2048 + ((4 + g) * 2 + hi) * 128 + l31 * 4);
#pragma unroll
            for (int rr = 0; rr < 4; ++rr) {
                const int qrow = rr + 8 * g + 4 * hi;   // (r&3)+8*(r>>2)+4*hi
                const float inv = __builtin_amdgcn_rcpf(
                    sL[qg * 32 + qrow] + sL[128 + qg * 32 + qrow] - nm);
                const int s = qt * 128 + qg * 32 + qrow;
                const size_t base = ((size_t)(b * S_ + s)) * D_ + h * 64 + l31;
                Xc[base]      = f2bf((oc[0][g * 4 + rr] + oA[rr]) * inv);
                Xc[base + 32] = f2bf((oc[1][g * 4 + rr] + oB[rr]) * inv);
            }
        }
    }
}

// ---------------------------------------------------------------------------
extern "C" void kernel_launch(void* const* d_in, const int* in_sizes, int n_in,
                              void* d_out, int out_size, void* d_ws, size_t ws_size,
                              hipStream_t stream)
{
    (void)in_sizes; (void)n_in; (void)out_size; (void)ws_size;

    const float* query = (const float*)d_in[0];
    const float* key   = (const float*)d_in[1];
    const float* value = (const float*)d_in[2];
    const int*   mask  = (const int*)d_in[3];
    const float* wq    = (const float*)d_in[4];
    const float* bq    = (const float*)d_in[5];
    const float* wk    = (const float*)d_in[6];
    const float* bk    = (const float*)d_in[7];
    const float* wv    = (const float*)d_in[8];
    const float* bv    = (const float*)d_in[9];
    const float* wo    = (const float*)d_in[10];
    const float* bo    = (const float*)d_in[11];

    const size_t NE = (size_t)B_ * S_ * D_;   // 4,194,304
    const size_t WE = (size_t)D_ * D_;        // 1,048,576

    u16* qb  = (u16*)d_ws;      // bf16 inputs
    u16* kb  = qb + NE;
    u16* vb  = kb + NE;
    u16* wqb = vb + NE;         // bf16 weights
    u16* wkb = wqb + WE;
    u16* wvb = wkb + WE;
    u16* wob = wvb + WE;
    u16* Qp  = wob + WE;        // projected heads
    u16* Kp  = Qp + NE;
    u16* Vt  = Kp + NE;         // V transposed: [h*64+dk][b*2048+s]
    float* mfac   = (float*)(Vt + NE);   // 4096 f32 mask factors (1/0)
    float* nmaskf = mfac + 4096;         // 2 f32 masked-key counts
    u16* Xc  = qb;              // alias: qb is dead after qkv_gemm

    cast_all<<<2066, 256, 0, stream>>>(query, key, value, wq, wk, wv, wo, mask,
                                       qb, kb, vb, wqb, wkb, wvb, wob, mfac, nmaskf);

    qkv_gemm<<<1536, 256, 0, stream>>>(
        qb, kb, vb, wqb, wkb, wvb, bq, bk, bv, Qp, Kp, Vt, mfac);

    attn_mfma<<<512, 512, 0, stream>>>(Qp, Kp, Vt, nmaskf, Xc);

    out_gemm<<<1024, 256, 0, stream>>>(Xc, wob, bo, (float*)d_out);
}